// Round 9
// baseline (163.775 us; speedup 1.0000x reference)
//
#include <hip/hip_runtime.h>
#include <math.h>

// ---------------------------------------------------------------------------
// HDRL Poincare MLR, c=1.
//   arg = 2*(Bc*xa - Aq*pa) / (Bc*(1-x2)*an),  Aq = 1+x2-2px, Bc = 1-p2
//   out = copysign(asinh(|arg|), arg) * an      (Dd cancels exactly; Dd>0)
// px = <x_b, p_o>, xa = <x_b, a_o> via dual bf16 MFMA GEMM (shared x tiles).
//
// R8: TLP instead of schedule heroics. 256-thread blocks (4 waves 2Mx2N),
//     128x128-dual tile, BK=32, static 48 KB LDS -> 2 blocks/CU. One block's
//     MFMA covers the other's stage/read/sync drain (m114 mechanism) — the
//     overlap that 1-block/CU R4-R7 structurally could not get.
//     BK=32 LDS rows stored PAIRED (r | r+64 -> 64-elem rows) so the verified
//     conflict-free XOR chunk swizzle still applies; staging source addr
//     absorbs pairing+swizzle (swizzle both-sides-or-neither).
// ---------------------------------------------------------------------------

#define B_DIM 8192
#define O_DIM 4096
#define K_DIM 1024

using f32x4  = __attribute__((ext_vector_type(4))) float;
using bf16x8 = __attribute__((ext_vector_type(8))) short;

__device__ inline unsigned short f2bf(float f) {
  union { float f; unsigned u; } v; v.f = f;
  unsigned u = v.u;
  u += 0x7FFFu + ((u >> 16) & 1u);   // RNE
  return (unsigned short)(u >> 16);
}

__device__ inline void load_lds16(const void* g, void* l) {
  __builtin_amdgcn_global_load_lds(
      (const __attribute__((address_space(1))) void*)g,
      (__attribute__((address_space(3))) void*)l, 16, 0, 0);
}

__device__ inline float frcp(float x)  { float r; asm("v_rcp_f32 %0, %1"  : "=v"(r) : "v"(x)); return r; }
__device__ inline float fsqrt_(float x){ float r; asm("v_sqrt_f32 %0, %1" : "=v"(r) : "v"(x)); return r; }
__device__ inline float flog2(float x) { float r; asm("v_log_f32 %0, %1"  : "=v"(r) : "v"(x)); return r; }

// ---- per-output-row stats + bf16 conversion (weight & projected bias) -----
__global__ __launch_bounds__(256) void prep_rows(
    const float* __restrict__ wgt, const float* __restrict__ bia,
    unsigned short* __restrict__ a_bf, unsigned short* __restrict__ p_bf,
    float* __restrict__ p2v, float* __restrict__ pav, float* __restrict__ anv)
{
  const int o = blockIdx.x, t = threadIdx.x;
  const float4 w = ((const float4*)(wgt + (size_t)o * K_DIM))[t];
  const float4 b = ((const float4*)(bia + (size_t)o * K_DIM))[t];
  float a2 = w.x*w.x + w.y*w.y + w.z*w.z + w.w*w.w;
  float b2 = b.x*b.x + b.y*b.y + b.z*b.z + b.w*b.w;
  float ab = w.x*b.x + w.y*b.y + w.z*b.z + w.w*b.w;
  #pragma unroll
  for (int off = 32; off; off >>= 1) {
    a2 += __shfl_down(a2, off);
    b2 += __shfl_down(b2, off);
    ab += __shfl_down(ab, off);
  }
  __shared__ float sa[4], sb[4], sc_[4];
  const int wv = t >> 6, ln = t & 63;
  if (ln == 0) { sa[wv] = a2; sb[wv] = b2; sc_[wv] = ab; }
  __syncthreads();
  const float A2 = sa[0] + sa[1] + sa[2] + sa[3];
  const float B2 = sb[0] + sb[1] + sb[2] + sb[3];
  const float AB = sc_[0] + sc_[1] + sc_[2] + sc_[3];
  const float norm = sqrtf(B2);
  const float maxn = 1.0f - 1e-5f;            // (1-PROJ_EPS)/sqrt(c), c=1
  const float s = (norm > maxn) ? (maxn / norm) : 1.0f;
  if (t == 0) { p2v[o] = B2 * s * s; pav[o] = AB * s; anv[o] = sqrtf(A2); }
  unsigned short* ao = a_bf + (size_t)o * K_DIM + t * 4;
  unsigned short* po = p_bf + (size_t)o * K_DIM + t * 4;
  ao[0] = f2bf(w.x); ao[1] = f2bf(w.y); ao[2] = f2bf(w.z); ao[3] = f2bf(w.w);
  po[0] = f2bf(b.x * s); po[1] = f2bf(b.y * s); po[2] = f2bf(b.z * s); po[3] = f2bf(b.w * s);
}

// ---- per-batch-row stats + bf16 conversion of x ---------------------------
__global__ __launch_bounds__(256) void prep_x(
    const float* __restrict__ x, unsigned short* __restrict__ x_bf,
    float* __restrict__ x2v)
{
  const int bi = blockIdx.x, t = threadIdx.x;
  const float4 v = ((const float4*)(x + (size_t)bi * K_DIM))[t];
  float s2 = v.x*v.x + v.y*v.y + v.z*v.z + v.w*v.w;
  #pragma unroll
  for (int off = 32; off; off >>= 1) s2 += __shfl_down(s2, off);
  __shared__ float sl[4];
  const int wv = t >> 6, ln = t & 63;
  if (ln == 0) sl[wv] = s2;
  __syncthreads();
  if (t == 0) x2v[bi] = sl[0] + sl[1] + sl[2] + sl[3];
  unsigned short* xo = x_bf + (size_t)bi * K_DIM + t * 4;
  xo[0] = f2bf(v.x); xo[1] = f2bf(v.y); xo[2] = f2bf(v.z); xo[3] = f2bf(v.w);
}

// ---- main dual-GEMM + fused epilogue ---------------------------------------
// 4 waves (2M x 2N). BM=128, BN=128 (dual P/W), BK=32. 32 K-tiles.
// LDS slot (bf16 elems, 24 KB): A-paired[64][64] @0 (rows r|r+64),
// P-paired[64][64] @4096, W-paired[64][64] @8192; 2 slots = 48 KB static.
// Pairing keeps 64-elem LDS rows -> conflict-free XOR chunk swizzle.
// 2 blocks/CU: cross-block TLP hides stage/read/sync phases under MFMA.
__global__ __launch_bounds__(256, 2) void hdrl_main(
    const unsigned short* __restrict__ Xb,
    const unsigned short* __restrict__ Pb,
    const unsigned short* __restrict__ Ab,
    const float* __restrict__ x2v, const float* __restrict__ p2v,
    const float* __restrict__ pav, const float* __restrict__ anv,
    float* __restrict__ out)
{
  __shared__ unsigned short lds[2 * 12288];

  const int bid   = blockIdx.x;
  const int xcd   = bid & 7;
  const int local = bid >> 3;                 // 0..255 per XCD
  const int nt    = xcd * 4 + (local & 3);    // 4 n-columns per XCD
  const int mt    = local >> 2;               // 0..63
  const int row0 = mt * 128, col0 = nt * 128;
  const int t    = threadIdx.x;
  const int wvL  = t >> 6, lane = t & 63;
  const int wm   = wvL >> 1, wn = wvL & 1;    // 2M x 2N waves
  const int lrow = lane & 15, kg = lane >> 4;
  const int sw   = lrow & 7;                  // read-side XOR key (chunks)

  // ---- staging addressing (pairing + inverse swizzle baked into source) ---
  // op(q, region): thread t -> LDS row lr = q*32 + (t>>3), chunk c = t&7.
  // logical chunk cl = c ^ (lr&7); source row += (cl>>2)*64 (pairing),
  // source k-offset = (cl&3)*8.
  const int lr0   = t >> 3;                   // q=0 LDS row (0..31)
  const int cl    = (t & 7) ^ (lr0 & 7);      // same for q=0,1 (q*32 = 0 mod 8)
  const int prOff = (cl >> 2) * 64;
  const int kk8   = (cl & 3) * 8;
  const unsigned short* gA = Xb + (size_t)(row0 + lr0 + prOff) * K_DIM + kk8;
  const unsigned short* gP = Pb + (size_t)(col0 + lr0 + prOff) * K_DIM + kk8;
  const unsigned short* gW = Ab + (size_t)(col0 + lr0 + prOff) * K_DIM + kk8;

  // ---- read offsets (elems, within slot) ----------------------------------
  // af[i]: A row R = wm*64+i*16+lrow -> LDS row (i*16+lrow), chunk (wm*4+kg)^sw
  // bp[j]/bw[j]: col C = wn*64+j*16+lrow -> LDS row (j*16+lrow), chunk (wn*4+kg)^sw
  const int chA = ((wm * 4 + kg) ^ sw) * 8;
  const int chB = ((wn * 4 + kg) ^ sw) * 8;

  f32x4 accp[4][4], acca[4][4];
  #pragma unroll
  for (int i = 0; i < 4; ++i)
    #pragma unroll
    for (int j = 0; j < 4; ++j) { accp[i][j] = (f32x4)0.0f; acca[i][j] = (f32x4)0.0f; }

#define STAGE(slot, k0n)                                                      \
  do {                                                                        \
    load_lds16(gA + (k0n),                (void*)&lds[(slot)*12288 +        wvL*512]); \
    load_lds16(gA + (size_t)32*K_DIM+(k0n),(void*)&lds[(slot)*12288 + 2048 + wvL*512]); \
    load_lds16(gP + (k0n),                (void*)&lds[(slot)*12288 + 4096 + wvL*512]); \
    load_lds16(gP + (size_t)32*K_DIM+(k0n),(void*)&lds[(slot)*12288 + 6144 + wvL*512]); \
    load_lds16(gW + (k0n),                (void*)&lds[(slot)*12288 + 8192 + wvL*512]); \
    load_lds16(gW + (size_t)32*K_DIM+(k0n),(void*)&lds[(slot)*12288 +10240 + wvL*512]); \
  } while (0)

  // prologue: stage tile 0 into slot 0
  STAGE(0, 0);
  __syncthreads();

  for (int kt = 0; kt < 32; ++kt) {
    const int cur = kt & 1;
    const int cb  = cur * 12288;

    // stage next tile into the other slot (lands during this tile's MFMAs
    // and, with 2 blocks/CU, during the partner block's compute)
    if (kt < 31) STAGE(cur ^ 1, (size_t)(kt + 1) * 32);

    bf16x8 af[4], bp[4], bw[4];
    #pragma unroll
    for (int i = 0; i < 4; ++i)
      af[i] = *(const bf16x8*)&lds[cb + (i * 16 + lrow) * 64 + chA];
    #pragma unroll
    for (int j = 0; j < 4; ++j) {
      bp[j] = *(const bf16x8*)&lds[cb + 4096 + (j * 16 + lrow) * 64 + chB];
      bw[j] = *(const bf16x8*)&lds[cb + 8192 + (j * 16 + lrow) * 64 + chB];
    }

    __builtin_amdgcn_s_setprio(1);
    #pragma unroll
    for (int i = 0; i < 4; ++i)
      #pragma unroll
      for (int j = 0; j < 4; ++j)
        accp[i][j] = __builtin_amdgcn_mfma_f32_16x16x32_bf16(af[i], bp[j], accp[i][j], 0, 0, 0);
    #pragma unroll
    for (int i = 0; i < 4; ++i)
      #pragma unroll
      for (int j = 0; j < 4; ++j)
        acca[i][j] = __builtin_amdgcn_mfma_f32_16x16x32_bf16(af[i], bw[j], acca[i][j], 0, 0, 0);
    __builtin_amdgcn_s_setprio(0);

    __syncthreads();   // drains vmcnt+lgkmcnt; partner block hides the drain
  }

  // fused epilogue: C/D layout col = lane&15, row = (lane>>4)*4 + reg.
  // arg = 2*(Bc*xa - Aq*pa) / (Bc*(1-x2)*an); out = copysign(asinh|arg|,arg)*an
  float Bcj[4], paj[4], dja[4], lcj[4];
  #pragma unroll
  for (int j = 0; j < 4; ++j) {
    const int col = col0 + wn * 64 + j * 16 + lrow;
    const float Bc = 1.0f - p2v[col];
    const float an = anv[col];
    Bcj[j] = Bc; paj[j] = pav[col];
    dja[j] = Bc * an;                 // denom col factor
    lcj[j] = 0.69314718f * an;        // ln2 * a_norm
  }
  #pragma unroll
  for (int i = 0; i < 4; ++i) {
    const int rbase = row0 + wm * 64 + i * 16 + kg * 4;
    #pragma unroll
    for (int r = 0; r < 4; ++r) {
      const int row = rbase + r;
      const float x2 = x2v[row];
      const float Aqh = 1.0f + x2;
      const float omx = 1.0f - x2;
      float* orow = out + (size_t)row * O_DIM + col0 + wn * 64 + lrow;
      #pragma unroll
      for (int j = 0; j < 4; ++j) {
        const float px = accp[i][j][r];
        const float xa = acca[i][j][r];
        const float numer = Bcj[j] * xa - (Aqh - 2.0f * px) * paj[j];
        const float denom = dja[j] * omx + 1e-15f;
        const float arg = 2.0f * numer * frcp(denom);
        const float aa  = fabsf(arg);
        const float u   = aa + fsqrt_(__builtin_fmaf(aa, aa, 1.0f));
        orow[j * 16] = copysignf(flog2(u) * lcj[j], arg);
      }
    }
  }
#undef STAGE
}

extern "C" void kernel_launch(void* const* d_in, const int* in_sizes, int n_in,
                              void* d_out, int out_size, void* d_ws, size_t ws_size,
                              hipStream_t stream) {
  (void)in_sizes; (void)n_in; (void)out_size; (void)ws_size;
  const float* x = (const float*)d_in[0];
  const float* w = (const float*)d_in[1];
  const float* b = (const float*)d_in[2];
  float* out = (float*)d_out;

  char* ws = (char*)d_ws;
  unsigned short* x_bf = (unsigned short*)ws;                               // 16 MB
  unsigned short* p_bf = (unsigned short*)(ws + (size_t)16 * 1024 * 1024);  //  8 MB
  unsigned short* a_bf = (unsigned short*)(ws + (size_t)24 * 1024 * 1024);  //  8 MB
  float* p2v = (float*)(ws + (size_t)32 * 1024 * 1024);
  float* pav = p2v + O_DIM;
  float* anv = pav + O_DIM;
  float* x2v = anv + O_DIM;

  prep_rows<<<O_DIM, 256, 0, stream>>>(w, b, a_bf, p_bf, p2v, pav, anv);
  prep_x<<<B_DIM, 256, 0, stream>>>(x, x_bf, x2v);

  const int grid = (B_DIM / 128) * (O_DIM / 128);   // 2048
  hdrl_main<<<grid, 256, 0, stream>>>(x_bf, p_bf, a_bf, x2v, p2v, pav, anv, out);
}

// Round 10
// 150.343 us; speedup vs baseline: 1.0893x; 1.0893x over previous
//
#include <hip/hip_runtime.h>
#include <math.h>

// ---------------------------------------------------------------------------
// HDRL Poincare MLR, c=1.
//   arg = 2*(Bc*xa - Aq*pa) / (Bc*(1-x2)*an),  Aq = 1+x2-2px, Bc = 1-p2
//   out = copysign(asinh(|arg|), arg) * an      (Dd cancels exactly; Dd>0)
// px = <x_b, p_o>, xa = <x_b, a_o> via dual bf16 MFMA GEMM (shared x tiles).
//
// R9: m201-template port. 8 waves 2Mx4N (wave = 128 rows x 32 cols of BOTH
//     P and W). 4 phases per K-tile, each {ds_read | 2-gload stage -> BAR ->
//     lgkmcnt(0) -> setprio(1) -> 16 MFMA -> setprio(0) -> BAR}.
//     COUNTED vmcnt — never 0 in main loop (m218: counted vs drain0 =
//     +38-73%): ph4-end vmcnt(2) guarantees A,P(t+1); ph1-end vmcnt(2)
//     guarantees W(t). All prior rounds drained vmcnt(0) per tile — that
//     was the structural defect behind the 43% MfmaUtil plateau.
//     Keeps: XCD stripe (R4), XOR swizzle (R2), fast epilogue (R4).
// ---------------------------------------------------------------------------

#define B_DIM 8192
#define O_DIM 4096
#define K_DIM 1024

using f32x4  = __attribute__((ext_vector_type(4))) float;
using bf16x8 = __attribute__((ext_vector_type(8))) short;

__device__ inline unsigned short f2bf(float f) {
  union { float f; unsigned u; } v; v.f = f;
  unsigned u = v.u;
  u += 0x7FFFu + ((u >> 16) & 1u);   // RNE
  return (unsigned short)(u >> 16);
}

__device__ inline void load_lds16(const void* g, void* l) {
  __builtin_amdgcn_global_load_lds(
      (const __attribute__((address_space(1))) void*)g,
      (__attribute__((address_space(3))) void*)l, 16, 0, 0);
}

__device__ inline float frcp(float x)  { float r; asm("v_rcp_f32 %0, %1"  : "=v"(r) : "v"(x)); return r; }
__device__ inline float fsqrt_(float x){ float r; asm("v_sqrt_f32 %0, %1" : "=v"(r) : "v"(x)); return r; }
__device__ inline float flog2(float x) { float r; asm("v_log_f32 %0, %1"  : "=v"(r) : "v"(x)); return r; }

// ---- per-output-row stats + bf16 conversion (weight & projected bias) -----
__global__ __launch_bounds__(256) void prep_rows(
    const float* __restrict__ wgt, const float* __restrict__ bia,
    unsigned short* __restrict__ a_bf, unsigned short* __restrict__ p_bf,
    float* __restrict__ p2v, float* __restrict__ pav, float* __restrict__ anv)
{
  const int o = blockIdx.x, t = threadIdx.x;
  const float4 w = ((const float4*)(wgt + (size_t)o * K_DIM))[t];
  const float4 b = ((const float4*)(bia + (size_t)o * K_DIM))[t];
  float a2 = w.x*w.x + w.y*w.y + w.z*w.z + w.w*w.w;
  float b2 = b.x*b.x + b.y*b.y + b.z*b.z + b.w*b.w;
  float ab = w.x*b.x + w.y*b.y + w.z*b.z + w.w*b.w;
  #pragma unroll
  for (int off = 32; off; off >>= 1) {
    a2 += __shfl_down(a2, off);
    b2 += __shfl_down(b2, off);
    ab += __shfl_down(ab, off);
  }
  __shared__ float sa[4], sb[4], sc_[4];
  const int wv = t >> 6, ln = t & 63;
  if (ln == 0) { sa[wv] = a2; sb[wv] = b2; sc_[wv] = ab; }
  __syncthreads();
  const float A2 = sa[0] + sa[1] + sa[2] + sa[3];
  const float B2 = sb[0] + sb[1] + sb[2] + sb[3];
  const float AB = sc_[0] + sc_[1] + sc_[2] + sc_[3];
  const float norm = sqrtf(B2);
  const float maxn = 1.0f - 1e-5f;            // (1-PROJ_EPS)/sqrt(c), c=1
  const float s = (norm > maxn) ? (maxn / norm) : 1.0f;
  if (t == 0) { p2v[o] = B2 * s * s; pav[o] = AB * s; anv[o] = sqrtf(A2); }
  unsigned short* ao = a_bf + (size_t)o * K_DIM + t * 4;
  unsigned short* po = p_bf + (size_t)o * K_DIM + t * 4;
  ao[0] = f2bf(w.x); ao[1] = f2bf(w.y); ao[2] = f2bf(w.z); ao[3] = f2bf(w.w);
  po[0] = f2bf(b.x * s); po[1] = f2bf(b.y * s); po[2] = f2bf(b.z * s); po[3] = f2bf(b.w * s);
}

// ---- per-batch-row stats + bf16 conversion of x ---------------------------
__global__ __launch_bounds__(256) void prep_x(
    const float* __restrict__ x, unsigned short* __restrict__ x_bf,
    float* __restrict__ x2v)
{
  const int bi = blockIdx.x, t = threadIdx.x;
  const float4 v = ((const float4*)(x + (size_t)bi * K_DIM))[t];
  float s2 = v.x*v.x + v.y*v.y + v.z*v.z + v.w*v.w;
  #pragma unroll
  for (int off = 32; off; off >>= 1) s2 += __shfl_down(s2, off);
  __shared__ float sl[4];
  const int wv = t >> 6, ln = t & 63;
  if (ln == 0) sl[wv] = s2;
  __syncthreads();
  if (t == 0) x2v[bi] = sl[0] + sl[1] + sl[2] + sl[3];
  unsigned short* xo = x_bf + (size_t)bi * K_DIM + t * 4;
  xo[0] = f2bf(v.x); xo[1] = f2bf(v.y); xo[2] = f2bf(v.z); xo[3] = f2bf(v.w);
}

// ---- main dual-GEMM + fused epilogue ---------------------------------------
// 8 waves 2Mx4N: wm = wv>>2 (128-row strip), wn = wv&3 (32-col strip of both
// P and W). acc = 8i x 2j x 2(P,W) x f32x4 = 128 VGPR.
// LDS per buffer (bf16 elems): A[256*64]=16384 @0, P[128*64]=8192 @16384,
// W[128*64]=8192 @24576; buffer stride 32768 elems; 2 buffers = 128 KB.
// Phases/K-tile: [P k0 | W k0 | P k1 | W k1]; stage issue [A0|A1|P|W];
// vmcnt(2) at ph1-end (W(t) resident) and ph4-end (A,P(t+1) resident).
__global__ __launch_bounds__(512, 2) void hdrl_main(
    const unsigned short* __restrict__ Xb,
    const unsigned short* __restrict__ Pb,
    const unsigned short* __restrict__ Ab,
    const float* __restrict__ x2v, const float* __restrict__ p2v,
    const float* __restrict__ pav, const float* __restrict__ anv,
    float* __restrict__ out)
{
  extern __shared__ unsigned short lds[];

  const int bid   = blockIdx.x;
  const int xcd   = bid & 7;
  const int local = bid >> 3;                 // 0..127 per XCD
  const int nt    = xcd * 4 + (local & 3);    // 4 n-columns per XCD
  const int mt    = local >> 2;               // 0..31
  const int row0 = mt * 256, col0 = nt * 128;
  const int t    = threadIdx.x;
  const int wv   = t >> 6, lane = t & 63;
  const int wm   = wv >> 2, wn = wv & 3;      // 2M x 4N waves
  const int lrow = lane & 15, kg = lane >> 4;
  const int sw   = (lrow & 7) << 3;           // read-side XOR key (elems)
  const int kbs0 = (kg * 8) ^ sw;             // kk=0 chunk offset
  const int kbs1 = (32 + kg * 8) ^ sw;        // kk=1 chunk offset

  // staging: thread t covers chunk (r = q*64 + (t>>3), c = t&7), 16B chunks
  const int sr   = t >> 3;                    // 0..63
  const int sc   = t & 7;
  const int scol = (sc ^ (sr & 7)) * 8;       // inverse-swizzled source col
  const unsigned short* gA = Xb + (size_t)(row0 + sr) * K_DIM + scol;
  const unsigned short* gP = Pb + (size_t)(col0 + sr) * K_DIM + scol;
  const unsigned short* gW = Ab + (size_t)(col0 + sr) * K_DIM + scol;

  f32x4 accp[8][2], acca[8][2];
  #pragma unroll
  for (int i = 0; i < 8; ++i)
    #pragma unroll
    for (int j = 0; j < 2; ++j) { accp[i][j] = (f32x4)0.0f; acca[i][j] = (f32x4)0.0f; }

#define STAGE_A(q) load_lds16(gA + (size_t)(q)*64*K_DIM + k0n, (void*)&lds[nb + (q)*4096 + wv*512])
#define STAGE_P(q) load_lds16(gP + (size_t)(q)*64*K_DIM + k0n, (void*)&lds[nb + 16384 + (q)*4096 + wv*512])
#define STAGE_W(q) load_lds16(gW + (size_t)(q)*64*K_DIM + k0n, (void*)&lds[nb + 24576 + (q)*4096 + wv*512])
#define BAR()   __builtin_amdgcn_s_barrier()
#define LGKM0() asm volatile("s_waitcnt lgkmcnt(0)" ::: "memory")

  // prologue: stage tile 0 into buffer 0; guarantee A,P(0) (W(0) still flies)
  {
    const int nb = 0, k0n = 0;
    STAGE_A(0); STAGE_A(1); STAGE_A(2); STAGE_A(3);
    STAGE_P(0); STAGE_P(1); STAGE_W(0); STAGE_W(1);
  }
  asm volatile("s_waitcnt vmcnt(2)" ::: "memory");
  BAR();

  bf16x8 af[8], bf0, bf1;

  for (int kt = 0; kt < 16; ++kt) {
    const int cur = kt & 1;
    const int cb  = cur * 32768;
    const int nb  = (cur ^ 1) * 32768;
    const int k0n = (kt + 1) * 64;
    const bool pf = (kt < 15);
    const int arow = wm * 128 + lrow;          // A frag base row
    const int brow = wn * 32 + lrow;           // B frag base row (P/W region)

    // ---- phase 1: read A[k0] + P[k0]; stage A0(t+1); MFMA P k0 ------------
    #pragma unroll
    for (int i = 0; i < 8; ++i)
      af[i] = *(const bf16x8*)&lds[cb + (arow + i * 16) * 64 + kbs0];
    bf0 = *(const bf16x8*)&lds[cb + 16384 + (brow +  0) * 64 + kbs0];
    bf1 = *(const bf16x8*)&lds[cb + 16384 + (brow + 16) * 64 + kbs0];
    if (pf) { STAGE_A(0); STAGE_A(1); }
    BAR(); LGKM0();
    __builtin_amdgcn_s_setprio(1);
    #pragma unroll
    for (int i = 0; i < 8; ++i) {
      accp[i][0] = __builtin_amdgcn_mfma_f32_16x16x32_bf16(af[i], bf0, accp[i][0], 0, 0, 0);
      accp[i][1] = __builtin_amdgcn_mfma_f32_16x16x32_bf16(af[i], bf1, accp[i][1], 0, 0, 0);
    }
    __builtin_amdgcn_s_setprio(0);
    if (pf) asm volatile("s_waitcnt vmcnt(2)" ::: "memory");   // W(t) resident
    else    asm volatile("s_waitcnt vmcnt(0)" ::: "memory");
    BAR();

    // ---- phase 2: read W[k0]; stage A1(t+1); MFMA W k0 --------------------
    bf0 = *(const bf16x8*)&lds[cb + 24576 + (brow +  0) * 64 + kbs0];
    bf1 = *(const bf16x8*)&lds[cb + 24576 + (brow + 16) * 64 + kbs0];
    if (pf) { STAGE_A(2); STAGE_A(3); }
    BAR(); LGKM0();
    __builtin_amdgcn_s_setprio(1);
    #pragma unroll
    for (int i = 0; i < 8; ++i) {
      acca[i][0] = __builtin_amdgcn_mfma_f32_16x16x32_bf16(af[i], bf0, acca[i][0], 0, 0, 0);
      acca[i][1] = __builtin_amdgcn_mfma_f32_16x16x32_bf16(af[i], bf1, acca[i][1], 0, 0, 0);
    }
    __builtin_amdgcn_s_setprio(0);
    BAR();

    // ---- phase 3: read A[k1] + P[k1]; stage P(t+1); MFMA P k1 -------------
    #pragma unroll
    for (int i = 0; i < 8; ++i)
      af[i] = *(const bf16x8*)&lds[cb + (arow + i * 16) * 64 + kbs1];
    bf0 = *(const bf16x8*)&lds[cb + 16384 + (brow +  0) * 64 + kbs1];
    bf1 = *(const bf16x8*)&lds[cb + 16384 + (brow + 16) * 64 + kbs1];
    if (pf) { STAGE_P(0); STAGE_P(1); }
    BAR(); LGKM0();
    __builtin_amdgcn_s_setprio(1);
    #pragma unroll
    for (int i = 0; i < 8; ++i) {
      accp[i][0] = __builtin_amdgcn_mfma_f32_16x16x32_bf16(af[i], bf0, accp[i][0], 0, 0, 0);
      accp[i][1] = __builtin_amdgcn_mfma_f32_16x16x32_bf16(af[i], bf1, accp[i][1], 0, 0, 0);
    }
    __builtin_amdgcn_s_setprio(0);
    BAR();

    // ---- phase 4: read W[k1]; stage W(t+1); MFMA W k1; vmcnt(2) -----------
    bf0 = *(const bf16x8*)&lds[cb + 24576 + (brow +  0) * 64 + kbs1];
    bf1 = *(const bf16x8*)&lds[cb + 24576 + (brow + 16) * 64 + kbs1];
    if (pf) { STAGE_W(0); STAGE_W(1); }
    BAR(); LGKM0();
    __builtin_amdgcn_s_setprio(1);
    #pragma unroll
    for (int i = 0; i < 8; ++i) {
      acca[i][0] = __builtin_amdgcn_mfma_f32_16x16x32_bf16(af[i], bf0, acca[i][0], 0, 0, 0);
      acca[i][1] = __builtin_amdgcn_mfma_f32_16x16x32_bf16(af[i], bf1, acca[i][1], 0, 0, 0);
    }
    __builtin_amdgcn_s_setprio(0);
    asm volatile("s_waitcnt vmcnt(2)" ::: "memory");   // A,P(t+1) resident
    BAR();
  }

  // fused epilogue: C/D layout col = lane&15, row = (lane>>4)*4 + reg.
  // arg = 2*(Bc*xa - Aq*pa) / (Bc*(1-x2)*an); out = copysign(asinh|arg|,arg)*an
  float Bcj[2], paj[2], dja[2], lcj[2];
  #pragma unroll
  for (int j = 0; j < 2; ++j) {
    const int col = col0 + wn * 32 + j * 16 + lrow;
    const float Bc = 1.0f - p2v[col];
    const float an = anv[col];
    Bcj[j] = Bc; paj[j] = pav[col];
    dja[j] = Bc * an;                 // denom col factor
    lcj[j] = 0.69314718f * an;        // ln2 * a_norm
  }
  #pragma unroll
  for (int i = 0; i < 8; ++i) {
    const int rbase = row0 + wm * 128 + i * 16 + kg * 4;
    #pragma unroll
    for (int r = 0; r < 4; ++r) {
      const int row = rbase + r;
      const float x2 = x2v[row];
      const float Aqh = 1.0f + x2;
      const float omx = 1.0f - x2;
      float* orow = out + (size_t)row * O_DIM + col0 + wn * 32 + lrow;
      #pragma unroll
      for (int j = 0; j < 2; ++j) {
        const float px = accp[i][j][r];
        const float xa = acca[i][j][r];
        const float numer = Bcj[j] * xa - (Aqh - 2.0f * px) * paj[j];
        const float denom = dja[j] * omx + 1e-15f;
        const float arg = 2.0f * numer * frcp(denom);
        const float aa  = fabsf(arg);
        const float u   = aa + fsqrt_(__builtin_fmaf(aa, aa, 1.0f));
        orow[j * 16] = copysignf(flog2(u) * lcj[j], arg);
      }
    }
  }
#undef STAGE_A
#undef STAGE_P
#undef STAGE_W
#undef BAR
#undef LGKM0
}

extern "C" void kernel_launch(void* const* d_in, const int* in_sizes, int n_in,
                              void* d_out, int out_size, void* d_ws, size_t ws_size,
                              hipStream_t stream) {
  (void)in_sizes; (void)n_in; (void)out_size; (void)ws_size;
  const float* x = (const float*)d_in[0];
  const float* w = (const float*)d_in[1];
  const float* b = (const float*)d_in[2];
  float* out = (float*)d_out;

  char* ws = (char*)d_ws;
  unsigned short* x_bf = (unsigned short*)ws;                               // 16 MB
  unsigned short* p_bf = (unsigned short*)(ws + (size_t)16 * 1024 * 1024);  //  8 MB
  unsigned short* a_bf = (unsigned short*)(ws + (size_t)24 * 1024 * 1024);  //  8 MB
  float* p2v = (float*)(ws + (size_t)32 * 1024 * 1024);
  float* pav = p2v + O_DIM;
  float* anv = pav + O_DIM;
  float* x2v = anv + O_DIM;

  prep_rows<<<O_DIM, 256, 0, stream>>>(w, b, a_bf, p_bf, p2v, pav, anv);
  prep_x<<<B_DIM, 256, 0, stream>>>(x, x_bf, x2v);

  hipFuncSetAttribute((const void*)hdrl_main,
                      hipFuncAttributeMaxDynamicSharedMemorySize, 131072);
  const int grid = (B_DIM / 256) * (O_DIM / 128);   // 1024
  hdrl_main<<<grid, 512, 131072, stream>>>(x_bf, p_bf, a_bf, x2v, p2v, pav, anv, out);
}